// Round 1
// 254.108 us; speedup vs baseline: 1.0046x; 1.0046x over previous
//
#include <hip/hip_runtime.h>
#include <stdint.h>

#define BB 128
#define NN 32768
#define CI 6
#define TOPK 400
#define KEEPK 200
#define SORTN 1024
#define NT 1024
#define KQT 8              // uint4 per thread: 8*4 = 32 keys = NN / NT
#define NBUCK 4096
#define KEY0 0x3F000000u   // float bits of 0.5f

// ---------------- K1: full-GPU score pass ----------------
// key = float bits of score if score > 0.5 else 0. Positive float bits are
// order-isomorphic to values. One thread per row; 16384 blocks saturate all
// 256 CUs at HBM rate.
__global__ __launch_bounds__(256) void score_kernel(
        const float* __restrict__ pred, uint32_t* __restrict__ keys) {
    int g = blockIdx.x * 256 + threadIdx.x;          // global row 0..B*N-1
    float2 c = *reinterpret_cast<const float2*>(pred + (size_t)g * CI + 4);
    float s = fmaxf(c.x, c.y);
    keys[g] = (s > 0.5f) ? __float_as_uint(s) : 0u;
}

// ---------------- K2: per-image select + sort + decode + NMS ----------------
// Single-pass 4096-bucket select exploiting bounded key range
// [0x3F000000, ~0x41000000): bucket = min(4095,(key-KEY0)>>13). Gather all
// keys in buckets >= B (where count(>B) < 400 <= count(>=B)), bitonic-sort
// 1024 desc by (key, ~idx) -> exact reference top_k order. Decode / NMS /
// resolve / rank phases identical to the previously verified kernel.
__global__ __launch_bounds__(NT) void boxsel2_kernel(
        const float* __restrict__ pred, const float* __restrict__ priors,
        const uint32_t* __restrict__ keys, float* __restrict__ out) {
    const int b = blockIdx.x;
    const int tid = threadIdx.x;
    const int lane = tid & 63;
    const int wid = tid >> 6;                 // 0..15
    const float* img = pred + (size_t)b * (NN * CI);
    float* oimg = out + (size_t)b * KEEPK * 6;

    __shared__ union {
        unsigned int hist[4][NBUCK];          // 64 KB, phase 2 only
        struct {                              // phases 3-8 (after hist dead)
            unsigned long long cbuf[SORTN];               // 8 KB
            float4 cbox[TOPK];                            // 6.4 KB
            float car[TOPK], csc[TOPK];                   // 3.2 KB
            int clab[TOPK];                               // 1.6 KB
            unsigned long long supm[TOPK * 7 + 8];        // 22.5 KB
        } s;
    } u;
    __shared__ unsigned int wavetot[16];
    __shared__ unsigned int sh_bucket, sh_above, ccount;
    __shared__ unsigned long long keepw[8];

    // zero output rows (d_out poisoned before every launch)
    for (int i = tid; i < KEEPK * 6; i += NT) oimg[i] = 0.0f;

    // ---- phase 1: coalesced uint4 key load (128 KB per image)
    uint4 kq[KQT];
    const uint4* k4 = reinterpret_cast<const uint4*>(keys + (size_t)b * NN);
#pragma unroll
    for (int uu = 0; uu < KQT; uu++) kq[uu] = k4[tid + (uu << 10)];

    if (tid == 0) { sh_bucket = 0; sh_above = 0; ccount = 0; }
    if (tid < 8) keepw[tid] = 0ull;
    for (int i = tid; i < 4 * NBUCK; i += NT) ((unsigned int*)u.hist)[i] = 0u;
    __syncthreads();

    // ---- phase 2a: single-pass histogram, 4 copies (contention ~nil:
    // hottest bucket ~16-30 keys out of ~17K candidates)
    const int hc = wid & 3;
#pragma unroll
    for (int uu = 0; uu < KQT; uu++) {
        uint32_t k0 = kq[uu].x, k1 = kq[uu].y, k2 = kq[uu].z, k3 = kq[uu].w;
        if (k0) { unsigned int bu = (k0 - KEY0) >> 13; if (bu > NBUCK - 1u) bu = NBUCK - 1u; atomicAdd(&u.hist[hc][bu], 1u); }
        if (k1) { unsigned int bu = (k1 - KEY0) >> 13; if (bu > NBUCK - 1u) bu = NBUCK - 1u; atomicAdd(&u.hist[hc][bu], 1u); }
        if (k2) { unsigned int bu = (k2 - KEY0) >> 13; if (bu > NBUCK - 1u) bu = NBUCK - 1u; atomicAdd(&u.hist[hc][bu], 1u); }
        if (k3) { unsigned int bu = (k3 - KEY0) >> 13; if (bu > NBUCK - 1u) bu = NBUCK - 1u; atomicAdd(&u.hist[hc][bu], 1u); }
    }
    __syncthreads();

    // ---- phase 2b: merge copies + suffix scan; thread owns buckets 4t..4t+3
    unsigned int h0 = u.hist[0][4 * tid + 0] + u.hist[1][4 * tid + 0] + u.hist[2][4 * tid + 0] + u.hist[3][4 * tid + 0];
    unsigned int h1 = u.hist[0][4 * tid + 1] + u.hist[1][4 * tid + 1] + u.hist[2][4 * tid + 1] + u.hist[3][4 * tid + 1];
    unsigned int h2 = u.hist[0][4 * tid + 2] + u.hist[1][4 * tid + 2] + u.hist[2][4 * tid + 2] + u.hist[3][4 * tid + 2];
    unsigned int h3 = u.hist[0][4 * tid + 3] + u.hist[1][4 * tid + 3] + u.hist[2][4 * tid + 3] + u.hist[3][4 * tid + 3];
    unsigned int sum = h0 + h1 + h2 + h3;
    // wave-level inclusive suffix sum (higher lane = higher buckets)
    unsigned int suf = sum;
#pragma unroll
    for (int off = 1; off < 64; off <<= 1) {
        unsigned int v = __shfl_down(suf, off);
        if (lane + off < 64) suf += v;
    }
    if (lane == 0) wavetot[wid] = suf;
    __syncthreads();
    if (tid < 16) {                           // exclusive suffix over waves
        unsigned int wv = wavetot[tid];
        unsigned int ws = wv;
#pragma unroll
        for (int off = 1; off < 16; off <<= 1) {
            unsigned int v = __shfl_down(ws, off);
            if (tid + off < 16) ws += v;
        }
        wavetot[tid] = ws - wv;
    }
    __syncthreads();
    unsigned int acc = wavetot[wid] + (suf - sum);   // count strictly above my 4
    if (acc < TOPK && acc + h3 >= TOPK) { sh_bucket = 4 * tid + 3; sh_above = acc; }
    acc += h3;
    if (acc < TOPK && acc + h2 >= TOPK) { sh_bucket = 4 * tid + 2; sh_above = acc; }
    acc += h2;
    if (acc < TOPK && acc + h1 >= TOPK) { sh_bucket = 4 * tid + 1; sh_above = acc; }
    acc += h1;
    if (acc < TOPK && acc + h0 >= TOPK) { sh_bucket = 4 * tid + 0; sh_above = acc; }
    __syncthreads();
    const unsigned int B = sh_bucket;         // 0 if fewer than 400 candidates

    // ---- phase 3: gather composites (key, ~idx) for buckets >= B
    // (hist reads all completed before the barrier above; reuse LDS as cbuf)
    u.s.cbuf[tid] = 0ull;
    __syncthreads();
#pragma unroll
    for (int uu = 0; uu < KQT; uu++) {
        uint32_t kk[4] = { kq[uu].x, kq[uu].y, kq[uu].z, kq[uu].w };
#pragma unroll
        for (int j = 0; j < 4; j++) {
            uint32_t key = kk[j];
            if (key != 0u) {
                unsigned int bu = (key - KEY0) >> 13;
                if (bu > NBUCK - 1u) bu = NBUCK - 1u;
                if (bu >= B) {
                    unsigned int p = atomicAdd(&ccount, 1u);
                    if (p < SORTN) {
                        unsigned int idx = ((unsigned int)(tid + (uu << 10)) << 2) + (unsigned int)j;
                        u.s.cbuf[p] = ((unsigned long long)key << 32) |
                                      (unsigned long long)(0xFFFFFFFFu - idx);
                    }
                }
            }
        }
    }
    __syncthreads();

    // ---- phase 4: bitonic sort 1024 desc => exact top_k order (ties: lower idx)
    for (int kk = 2; kk <= SORTN; kk <<= 1) {
        for (int j = kk >> 1; j > 0; j >>= 1) {
            int partner = tid ^ j;
            if (partner > tid) {
                unsigned long long a = u.s.cbuf[tid], c = u.s.cbuf[partner];
                if (((tid & kk) == 0) ? (a < c) : (a > c)) {
                    u.s.cbuf[tid] = c; u.s.cbuf[partner] = a;
                }
            }
            __syncthreads();
        }
    }

    // ---- phase 5: decode candidates (reference float op order; no fma)
    if (tid < TOPK) {
        const int t = tid;
        unsigned long long c = u.s.cbuf[t];
        uint32_t key = (uint32_t)(c >> 32);
        uint32_t idx = 0xFFFFFFFFu - (uint32_t)(c & 0xFFFFFFFFull);
        int valid = (key != 0u) && (idx < NN);
        float x1 = 0.f, y1 = 0.f, x2 = 0.f, y2 = 0.f;
        int lab = 0;
        if (valid) {
            const float* p = img + (size_t)idx * CI;
            float l0 = p[0], l1 = p[1], l2 = p[2], l3 = p[3], c0 = p[4], c1 = p[5];
            const float* pr = priors + (size_t)idx * 4;
            float px = pr[0], py = pr[1], pw = pr[2], ph = pr[3];
            float cxv = __fadd_rn(px, __fmul_rn(__fmul_rn(l0, 0.1f), pw));
            float cyv = __fadd_rn(py, __fmul_rn(__fmul_rn(l1, 0.1f), ph));
            float ew = __fmul_rn(pw, expf(__fmul_rn(l2, 0.2f)));
            float eh = __fmul_rn(ph, expf(__fmul_rn(l3, 0.2f)));
            float hw = __fmul_rn(ew, 0.5f);
            float hh = __fmul_rn(eh, 0.5f);
            x1 = __fsub_rn(cxv, hw); y1 = __fsub_rn(cyv, hh);
            x2 = __fadd_rn(cxv, hw); y2 = __fadd_rn(cyv, hh);
            lab = (c1 > c0) ? 1 : 0;
        }
        u.s.cbox[t] = make_float4(x1, y1, x2, y2);
        u.s.csc[t] = __uint_as_float(key);
        u.s.car[t] = __fmul_rn(__fsub_rn(x2, x1), __fsub_rn(y2, y1));
        u.s.clab[t] = lab;
        if (valid) atomicOr(&keepw[t >> 6], 1ull << (t & 63));
    }
    __syncthreads();

    // ---- phase 6: suppression bit-matrix, upper triangle only
    for (int task = tid; task < TOPK * 7; task += NT) {
        int i = task / 7;
        int w4 = task - i * 7;
        int jbase = w4 << 6;
        int jmax = (TOPK - jbase < 64) ? (TOPK - jbase) : 64;
        int j0 = i + 1 - jbase; if (j0 < 0) j0 = 0;
        unsigned long long word = 0ull;
        if (j0 < jmax) {
            float4 bi = u.s.cbox[i]; float ai = u.s.car[i];
            for (int jj = j0; jj < jmax; jj++) {   // cbox[j]: broadcast reads
                int j = jbase + jj;
                float4 bj = u.s.cbox[j]; float aj = u.s.car[j];
                float iw = fmaxf(__fsub_rn(fminf(bi.z, bj.z), fmaxf(bi.x, bj.x)), 0.0f);
                float ih = fmaxf(__fsub_rn(fminf(bi.w, bj.w), fmaxf(bi.y, bj.y)), 0.0f);
                float inter = __fmul_rn(iw, ih);
                float denom = __fadd_rn(__fsub_rn(__fadd_rn(ai, aj), inter), 1e-12f);
                float iou = __fdiv_rn(inter, denom);
                if (iou > 0.5f) word |= (1ull << jj);
            }
        }
        u.s.supm[i * 7 + w4] = word;
    }
    __syncthreads();

    // ---- phase 7: sequential resolve in one wave, keep bits in registers
    if (tid < 64) {
        int w = tid & 7;                     // lanes 0-6 own words; rest shadow
        unsigned long long kw = keepw[w];
        unsigned long long nxt = u.s.supm[w];    // prefetch row 0 (w=7 reads pad)
        for (int i = 0; i < TOPK; i++) {
            unsigned long long cur = nxt;
            int ni = (i + 1 < TOPK) ? (i + 1) : i;
            nxt = u.s.supm[ni * 7 + w];
            unsigned long long wv = __shfl(kw, i >> 6);
            if ((wv >> (i & 63)) & 1ull) kw &= ~cur;
        }
        if (tid < 7) keepw[tid] = kw;
    }
    __syncthreads();

    // ---- phase 8: kept sorted ascending by (score, position), first 200 rows
    if (tid < TOPK) {
        const int t = tid;
        if ((keepw[t >> 6] >> (t & 63)) & 1ull) {
            float st = u.s.csc[t];
            int rank = 0;
            for (int j = 0; j < TOPK; j++) {
                bool kj = (keepw[j >> 6] >> (j & 63)) & 1ull;
                float sj = u.s.csc[j];
                if (kj && (sj < st || (sj == st && j < t))) rank++;
            }
            if (rank < KEEPK) {
                float4 bx = u.s.cbox[t];
                float* row = oimg + (size_t)rank * 6;
                row[0] = (float)u.s.clab[t];
                row[1] = st;
                row[2] = bx.x; row[3] = bx.y; row[4] = bx.z; row[5] = bx.w;
            }
        }
    }
}

extern "C" void kernel_launch(void* const* d_in, const int* in_sizes, int n_in,
                              void* d_out, int out_size, void* d_ws, size_t ws_size,
                              hipStream_t stream) {
    const float* pred = (const float*)d_in[0];     // (128, 32768, 6)
    const float* priors = (const float*)d_in[1];   // (32768, 4)
    float* out = (float*)d_out;                    // (128, 200, 6)
    uint32_t* keys = (uint32_t*)d_ws;              // 128*32768*4 = 16 MB scratch
    score_kernel<<<(BB * NN) / 256, 256, 0, stream>>>(pred, keys);
    boxsel2_kernel<<<BB, NT, 0, stream>>>(pred, priors, keys, out);
}

// Round 2
// 219.105 us; speedup vs baseline: 1.1650x; 1.1598x over previous
//
#include <hip/hip_runtime.h>
#include <stdint.h>

#define BB 128
#define NN 32768
#define CI 6
#define TOPK 400
#define KEEPK 200
#define SORTN 1024
#define NT 1024
#define KQT 8              // uint4 per thread: 8*4 = 32 keys = NN / NT
#define NBUCK 4096
#define KEY0 0x3F000000u   // float bits of 0.5f

// Exact-decision IoU constant: RN32(inter/denom) > 0.5f  <=>  inter > denom*(0.5+2^-25),
// and denom(24b) * C(26b) is exact in f64 -> bit-identical keep decisions without v_div.
#define IOU_C 0.50000002980232238769531250

// ---------------- K1: full-GPU score pass ----------------
// Thread handles rows 2g, 2g+1: conf floats live in float4 #1,#2 of the 48B
// row-pair -> two coalesced 16B loads, every fetched byte used. Coalesced
// uint2 key store.
__global__ __launch_bounds__(256) void score_kernel(
        const float* __restrict__ pred, uint32_t* __restrict__ keys) {
    int g = blockIdx.x * 256 + threadIdx.x;            // row-pair index
    const float4* p4 = reinterpret_cast<const float4*>(pred) + (size_t)g * 3;
    float4 b = p4[1];   // floats 12g+4..7 : c0,c1 of row 2g ; l0,l1 of row 2g+1
    float4 c = p4[2];   // floats 12g+8..11: l2,l3 of row 2g+1; c0,c1 of row 2g+1
    float s0 = fmaxf(b.x, b.y);
    float s1 = fmaxf(c.z, c.w);
    uint2 o;
    o.x = (s0 > 0.5f) ? __float_as_uint(s0) : 0u;
    o.y = (s1 > 0.5f) ? __float_as_uint(s1) : 0u;
    *reinterpret_cast<uint2*>(keys + (size_t)g * 2) = o;
}

// ---------------- K2: per-image select + order + decode + NMS ----------------
__global__ __launch_bounds__(NT) void boxsel2_kernel(
        const float* __restrict__ pred, const float* __restrict__ priors,
        const uint32_t* __restrict__ keys, float* __restrict__ out) {
    const int b = blockIdx.x;
    const int tid = threadIdx.x;
    const int lane = tid & 63;
    const int wid = tid >> 6;                 // 0..15
    const float* img = pred + (size_t)b * (NN * CI);
    float* oimg = out + (size_t)b * KEEPK * 6;

    __shared__ union {
        unsigned int hist[2][NBUCK];          // 32 KB, phase 2 only
        struct {                              // phases 3-8 (hist dead)
            unsigned long long cbuf[SORTN];               // gather (unordered)
            unsigned long long cbuf2[SORTN];              // rank-scattered (sorted)
            float4 cbox[TOPK];
            float car[TOPK], csc[TOPK];
            int clab[TOPK];
            unsigned long long supm[TOPK * 7 + 8];        // stride 7 + pad
        } s;
    } u;
    __shared__ unsigned int wavetot[16];
    __shared__ unsigned int sh_bucket, sh_above, ccount;
    __shared__ unsigned long long keepw[8];

    // zero output rows (d_out poisoned before every launch)
    for (int i = tid; i < KEEPK * 6; i += NT) oimg[i] = 0.0f;

    // ---- phase 1: coalesced uint4 key load (128 KB per image)
    uint4 kq[KQT];
    const uint4* k4 = reinterpret_cast<const uint4*>(keys + (size_t)b * NN);
#pragma unroll
    for (int uu = 0; uu < KQT; uu++) kq[uu] = k4[tid + (uu << 10)];

    if (tid == 0) { sh_bucket = 0; sh_above = 0; ccount = 0; }
    if (tid < 8) keepw[tid] = 0ull;
    for (int i = tid; i < 2 * NBUCK; i += NT) ((unsigned int*)u.hist)[i] = 0u;
    __syncthreads();

    // ---- phase 2a: single-pass histogram, 2 copies (avg ~8 keys/bucket)
    const int hc = wid & 1;
#pragma unroll
    for (int uu = 0; uu < KQT; uu++) {
        uint32_t k0 = kq[uu].x, k1 = kq[uu].y, k2 = kq[uu].z, k3 = kq[uu].w;
        if (k0) { unsigned int bu = (k0 - KEY0) >> 13; if (bu > NBUCK - 1u) bu = NBUCK - 1u; atomicAdd(&u.hist[hc][bu], 1u); }
        if (k1) { unsigned int bu = (k1 - KEY0) >> 13; if (bu > NBUCK - 1u) bu = NBUCK - 1u; atomicAdd(&u.hist[hc][bu], 1u); }
        if (k2) { unsigned int bu = (k2 - KEY0) >> 13; if (bu > NBUCK - 1u) bu = NBUCK - 1u; atomicAdd(&u.hist[hc][bu], 1u); }
        if (k3) { unsigned int bu = (k3 - KEY0) >> 13; if (bu > NBUCK - 1u) bu = NBUCK - 1u; atomicAdd(&u.hist[hc][bu], 1u); }
    }
    __syncthreads();

    // ---- phase 2b: merge copies + suffix scan; thread owns buckets 4t..4t+3
    unsigned int h0 = u.hist[0][4 * tid + 0] + u.hist[1][4 * tid + 0];
    unsigned int h1 = u.hist[0][4 * tid + 1] + u.hist[1][4 * tid + 1];
    unsigned int h2 = u.hist[0][4 * tid + 2] + u.hist[1][4 * tid + 2];
    unsigned int h3 = u.hist[0][4 * tid + 3] + u.hist[1][4 * tid + 3];
    unsigned int sum = h0 + h1 + h2 + h3;
    unsigned int suf = sum;                   // wave inclusive suffix sum
#pragma unroll
    for (int off = 1; off < 64; off <<= 1) {
        unsigned int v = __shfl_down(suf, off);
        if (lane + off < 64) suf += v;
    }
    if (lane == 0) wavetot[wid] = suf;
    __syncthreads();
    if (tid < 16) {                           // exclusive suffix over waves
        unsigned int wv = wavetot[tid];
        unsigned int ws = wv;
#pragma unroll
        for (int off = 1; off < 16; off <<= 1) {
            unsigned int v = __shfl_down(ws, off);
            if (tid + off < 16) ws += v;
        }
        wavetot[tid] = ws - wv;
    }
    __syncthreads();
    unsigned int acc = wavetot[wid] + (suf - sum);   // count strictly above my 4
    if (acc < TOPK && acc + h3 >= TOPK) { sh_bucket = 4 * tid + 3; sh_above = acc; }
    acc += h3;
    if (acc < TOPK && acc + h2 >= TOPK) { sh_bucket = 4 * tid + 2; sh_above = acc; }
    acc += h2;
    if (acc < TOPK && acc + h1 >= TOPK) { sh_bucket = 4 * tid + 1; sh_above = acc; }
    acc += h1;
    if (acc < TOPK && acc + h0 >= TOPK) { sh_bucket = 4 * tid + 0; sh_above = acc; }
    __syncthreads();
    const unsigned int B = sh_bucket;         // 0 if fewer than 400 candidates

    // ---- phase 3: gather composites (key, ~idx) for buckets >= B; zero cbuf2
    u.s.cbuf2[tid] = 0ull;
    __syncthreads();
#pragma unroll
    for (int uu = 0; uu < KQT; uu++) {
        uint32_t kk[4] = { kq[uu].x, kq[uu].y, kq[uu].z, kq[uu].w };
#pragma unroll
        for (int j = 0; j < 4; j++) {
            uint32_t key = kk[j];
            if (key != 0u) {
                unsigned int bu = (key - KEY0) >> 13;
                if (bu > NBUCK - 1u) bu = NBUCK - 1u;
                if (bu >= B) {
                    unsigned int p = atomicAdd(&ccount, 1u);
                    if (p < SORTN) {
                        unsigned int idx = ((unsigned int)(tid + (uu << 10)) << 2) + (unsigned int)j;
                        u.s.cbuf[p] = ((unsigned long long)key << 32) |
                                      (unsigned long long)(0xFFFFFFFFu - idx);
                    }
                }
            }
        }
    }
    __syncthreads();

    // ---- phase 4: rank-by-count scatter (exact desc order; composites are
    // distinct so ranks are a permutation). Broadcast LDS reads, no barriers.
    {
        const unsigned int cnt = (ccount < SORTN) ? ccount : SORTN;
        if ((unsigned int)tid < cnt) {
            unsigned long long ct = u.s.cbuf[tid];
            unsigned int rank = 0;
#pragma unroll 4
            for (unsigned int j = 0; j < cnt; j++)
                rank += (u.s.cbuf[j] > ct) ? 1u : 0u;
            u.s.cbuf2[rank] = ct;
        }
    }
    __syncthreads();

    // ---- phase 5: decode candidates (reference float op order; no fma)
    if (tid < TOPK) {
        const int t = tid;
        unsigned long long c = u.s.cbuf2[t];
        uint32_t key = (uint32_t)(c >> 32);
        uint32_t idx = 0xFFFFFFFFu - (uint32_t)(c & 0xFFFFFFFFull);
        int valid = (key != 0u) && (idx < NN);
        float x1 = 0.f, y1 = 0.f, x2 = 0.f, y2 = 0.f;
        int lab = 0;
        if (valid) {
            const float* p = img + (size_t)idx * CI;
            float l0 = p[0], l1 = p[1], l2 = p[2], l3 = p[3], c0 = p[4], c1 = p[5];
            const float* pr = priors + (size_t)idx * 4;
            float px = pr[0], py = pr[1], pw = pr[2], ph = pr[3];
            float cxv = __fadd_rn(px, __fmul_rn(__fmul_rn(l0, 0.1f), pw));
            float cyv = __fadd_rn(py, __fmul_rn(__fmul_rn(l1, 0.1f), ph));
            float ew = __fmul_rn(pw, expf(__fmul_rn(l2, 0.2f)));
            float eh = __fmul_rn(ph, expf(__fmul_rn(l3, 0.2f)));
            float hw = __fmul_rn(ew, 0.5f);
            float hh = __fmul_rn(eh, 0.5f);
            x1 = __fsub_rn(cxv, hw); y1 = __fsub_rn(cyv, hh);
            x2 = __fadd_rn(cxv, hw); y2 = __fadd_rn(cyv, hh);
            lab = (c1 > c0) ? 1 : 0;
        }
        u.s.cbox[t] = make_float4(x1, y1, x2, y2);
        u.s.csc[t] = __uint_as_float(key);
        u.s.car[t] = __fmul_rn(__fsub_rn(x2, x1), __fsub_rn(y2, y1));
        u.s.clab[t] = lab;
        if (valid) atomicOr(&keepw[t >> 6], 1ull << (t & 63));
    }
    __syncthreads();

    // ---- phase 6: suppression bit-matrix, upper triangle, div-free exact test
    for (int task = tid; task < TOPK * 7; task += NT) {
        int i = task / 7;
        int w4 = task - i * 7;
        int jbase = w4 << 6;
        int jmax = (TOPK - jbase < 64) ? (TOPK - jbase) : 64;
        int j0 = i + 1 - jbase; if (j0 < 0) j0 = 0;
        unsigned long long word = 0ull;
        if (j0 < jmax) {
            float4 bi = u.s.cbox[i]; float ai = u.s.car[i];
            for (int jj = j0; jj < jmax; jj++) {
                int j = jbase + jj;
                float4 bj = u.s.cbox[j]; float aj = u.s.car[j];
                float iw = fmaxf(__fsub_rn(fminf(bi.z, bj.z), fmaxf(bi.x, bj.x)), 0.0f);
                float ih = fmaxf(__fsub_rn(fminf(bi.w, bj.w), fmaxf(bi.y, bj.y)), 0.0f);
                float inter = __fmul_rn(iw, ih);
                float denom = __fadd_rn(__fsub_rn(__fadd_rn(ai, aj), inter), 1e-12f);
                if ((double)inter > (double)denom * IOU_C) word |= (1ull << jj);
            }
        }
        u.s.supm[i * 7 + w4] = word;
    }
    __syncthreads();

    // ---- phase 7: sequential resolve, one wave, 16-deep register prefetch
    if (tid < 64) {
        int w = tid & 7;                     // lanes 0-6 own words; rest shadow
        unsigned long long kw = keepw[w];
        unsigned long long rr[16], nn[16];   // compile-time-indexed after unroll
#pragma unroll
        for (int k = 0; k < 16; k++) rr[k] = u.s.supm[k * 7 + w];
        for (int base = 0; base < TOPK; base += 16) {
            int nb = base + 16;
            int gb = (nb < TOPK) ? nb : base;
#pragma unroll
            for (int k = 0; k < 16; k++) nn[k] = u.s.supm[(gb + k) * 7 + w];
#pragma unroll
            for (int k = 0; k < 16; k++) {
                int i = base + k;
                unsigned long long wv = __shfl(kw, i >> 6);
                if ((wv >> (i & 63)) & 1ull) kw &= ~rr[k];
            }
#pragma unroll
            for (int k = 0; k < 16; k++) rr[k] = nn[k];
        }
        if (tid < 7) keepw[tid] = kw;
    }
    __syncthreads();

    // ---- phase 8: rank via suffix-popcount over kept (csc is sorted desc),
    // exact tie correction by local walk (ties are O(0) for float scores).
    if (tid < TOPK) {
        const int t = tid;
        if ((keepw[t >> 6] >> (t & 63)) & 1ull) {
            float st = u.s.csc[t];
            int rank = 0;
#pragma unroll
            for (int w = 0; w < 7; w++) {
                unsigned long long kws = keepw[w];
                int jb = w << 6;
                unsigned long long m;
                if (t >= jb + 63)      m = 0ull;           // no bits > t here
                else if (t < jb)       m = ~0ull;          // whole word > t
                else                   m = ~((1ull << (t - jb + 1)) - 1ull);
                rank += __popcll(kws & m);
            }
            // kept j>t with sj==st were counted but rank below t in ref order
            for (int j = t + 1; j < TOPK && u.s.csc[j] == st; j++)
                if ((keepw[j >> 6] >> (j & 63)) & 1ull) rank--;
            // kept j<t with sj==st rank above t's strict-lower set
            for (int j = t - 1; j >= 0 && u.s.csc[j] == st; j--)
                if ((keepw[j >> 6] >> (j & 63)) & 1ull) rank++;
            if (rank < KEEPK) {
                float4 bx = u.s.cbox[t];
                float* row = oimg + (size_t)rank * 6;
                row[0] = (float)u.s.clab[t];
                row[1] = st;
                row[2] = bx.x; row[3] = bx.y; row[4] = bx.z; row[5] = bx.w;
            }
        }
    }
}

extern "C" void kernel_launch(void* const* d_in, const int* in_sizes, int n_in,
                              void* d_out, int out_size, void* d_ws, size_t ws_size,
                              hipStream_t stream) {
    const float* pred = (const float*)d_in[0];     // (128, 32768, 6)
    const float* priors = (const float*)d_in[1];   // (32768, 4)
    float* out = (float*)d_out;                    // (128, 200, 6)
    uint32_t* keys = (uint32_t*)d_ws;              // 16 MB scratch
    score_kernel<<<(BB * NN / 2) / 256, 256, 0, stream>>>(pred, keys);
    boxsel2_kernel<<<BB, NT, 0, stream>>>(pred, priors, keys, out);
}

// Round 3
// 204.921 us; speedup vs baseline: 1.2457x; 1.0692x over previous
//
#include <hip/hip_runtime.h>
#include <stdint.h>

#define BB 128
#define NN 32768
#define CI 6
#define TOPK 400
#define KEEPK 200
#define SORTN 1024
#define NT 1024
#define KQT 8              // uint4 per thread: 8*4 = 32 keys = NN / NT
#define NBUCK 4096
#define KEY0 0x3F000000u   // float bits of 0.5f

// Exact-decision IoU constant: RN32(inter/denom) > 0.5f  <=>  inter > denom*(0.5+2^-25),
// and denom(24b) * C(26b) is exact in f64 -> bit-identical keep decisions without v_div.
#define IOU_C 0.50000002980232238769531250

// ---------------- K1: full-GPU score pass ----------------
// Thread handles rows 2g, 2g+1 = one 48B row-pair, read DENSE as 3 float4s
// (leading quarter kept alive via asm so the coalescer sees a contiguous
// 48B/lane stream; those lines are fetched by HW anyway). Coalesced uint2
// key store.
__global__ __launch_bounds__(256) void score_kernel(
        const float* __restrict__ pred, uint32_t* __restrict__ keys) {
    int g = blockIdx.x * 256 + threadIdx.x;            // row-pair index
    const float4* p4 = reinterpret_cast<const float4*>(pred) + (size_t)g * 3;
    float4 a = p4[0];   // l0..l3 of row 2g (dead data, live load)
    float4 b = p4[1];   // c0,c1 of row 2g ; l0,l1 of row 2g+1
    float4 c = p4[2];   // l2,l3 of row 2g+1; c0,c1 of row 2g+1
    asm volatile("" :: "v"(a.x));                      // keep dense load (no DCE)
    float s0 = fmaxf(b.x, b.y);
    float s1 = fmaxf(c.z, c.w);
    uint2 o;
    o.x = (s0 > 0.5f) ? __float_as_uint(s0) : 0u;
    o.y = (s1 > 0.5f) ? __float_as_uint(s1) : 0u;
    *reinterpret_cast<uint2*>(keys + (size_t)g * 2) = o;
}

// ---------------- K2: per-image select + order + decode + NMS ----------------
__global__ __launch_bounds__(NT) void boxsel2_kernel(
        const float* __restrict__ pred, const float* __restrict__ priors,
        const uint32_t* __restrict__ keys, float* __restrict__ out) {
    const int b = blockIdx.x;
    const int tid = threadIdx.x;
    const int lane = tid & 63;
    const int wid = tid >> 6;                 // 0..15
    const float* img = pred + (size_t)b * (NN * CI);
    float* oimg = out + (size_t)b * KEEPK * 6;

    __shared__ union {
        unsigned int hist[2][NBUCK];          // 32 KB, phase 2 only
        struct {                              // phases 3-8 (hist dead)
            unsigned long long cbuf[SORTN];               // gather (unordered)
            unsigned long long cbuf2[SORTN];              // rank-scattered (sorted)
            float4 cbox[TOPK];
            float car[TOPK], csc[TOPK];
            int clab[TOPK];
            unsigned long long supm[TOPK * 7 + 8];        // stride 7 + pad
        } s;
    } u;
    __shared__ unsigned int wavetot[16];
    __shared__ unsigned int sh_bucket, ccount;
    __shared__ unsigned long long keepw[8];

    // zero output rows (d_out poisoned before every launch)
    for (int i = tid; i < KEEPK * 6; i += NT) oimg[i] = 0.0f;

    // ---- phase 1: coalesced uint4 key load (128 KB per image)
    uint4 kq[KQT];
    const uint4* k4 = reinterpret_cast<const uint4*>(keys + (size_t)b * NN);
#pragma unroll
    for (int uu = 0; uu < KQT; uu++) kq[uu] = k4[tid + (uu << 10)];

    if (tid == 0) { sh_bucket = 0; ccount = 0; }
    if (tid < 8) keepw[tid] = 0ull;
    for (int i = tid; i < 2 * NBUCK; i += NT) ((unsigned int*)u.hist)[i] = 0u;
    __syncthreads();

    // ---- phase 2a: single-pass histogram, 2 copies (avg ~8 keys/bucket)
    const int hc = wid & 1;
#pragma unroll
    for (int uu = 0; uu < KQT; uu++) {
        uint32_t k0 = kq[uu].x, k1 = kq[uu].y, k2 = kq[uu].z, k3 = kq[uu].w;
        if (k0) { unsigned int bu = (k0 - KEY0) >> 13; if (bu > NBUCK - 1u) bu = NBUCK - 1u; atomicAdd(&u.hist[hc][bu], 1u); }
        if (k1) { unsigned int bu = (k1 - KEY0) >> 13; if (bu > NBUCK - 1u) bu = NBUCK - 1u; atomicAdd(&u.hist[hc][bu], 1u); }
        if (k2) { unsigned int bu = (k2 - KEY0) >> 13; if (bu > NBUCK - 1u) bu = NBUCK - 1u; atomicAdd(&u.hist[hc][bu], 1u); }
        if (k3) { unsigned int bu = (k3 - KEY0) >> 13; if (bu > NBUCK - 1u) bu = NBUCK - 1u; atomicAdd(&u.hist[hc][bu], 1u); }
    }
    __syncthreads();

    // ---- phase 2b: merge copies + suffix scan; thread owns buckets 4t..4t+3
    unsigned int h0 = u.hist[0][4 * tid + 0] + u.hist[1][4 * tid + 0];
    unsigned int h1 = u.hist[0][4 * tid + 1] + u.hist[1][4 * tid + 1];
    unsigned int h2 = u.hist[0][4 * tid + 2] + u.hist[1][4 * tid + 2];
    unsigned int h3 = u.hist[0][4 * tid + 3] + u.hist[1][4 * tid + 3];
    unsigned int sum = h0 + h1 + h2 + h3;
    unsigned int suf = sum;                   // wave inclusive suffix sum
#pragma unroll
    for (int off = 1; off < 64; off <<= 1) {
        unsigned int v = __shfl_down(suf, off);
        if (lane + off < 64) suf += v;
    }
    if (lane == 0) wavetot[wid] = suf;
    __syncthreads();
    if (tid < 16) {                           // exclusive suffix over waves
        unsigned int wv = wavetot[tid];
        unsigned int ws = wv;
#pragma unroll
        for (int off = 1; off < 16; off <<= 1) {
            unsigned int v = __shfl_down(ws, off);
            if (tid + off < 16) ws += v;
        }
        wavetot[tid] = ws - wv;
    }
    __syncthreads();
    unsigned int acc = wavetot[wid] + (suf - sum);   // count strictly above my 4
    if (acc < TOPK && acc + h3 >= TOPK) sh_bucket = 4 * tid + 3;
    acc += h3;
    if (acc < TOPK && acc + h2 >= TOPK) sh_bucket = 4 * tid + 2;
    acc += h2;
    if (acc < TOPK && acc + h1 >= TOPK) sh_bucket = 4 * tid + 1;
    acc += h1;
    if (acc < TOPK && acc + h0 >= TOPK) sh_bucket = 4 * tid + 0;
    __syncthreads();
    // bucket(key) >= B  <=>  key >= KEY0 + (B<<13); all stored keys > KEY0,
    // so a single unsigned compare implements the gather predicate exactly.
    const uint32_t Tkey = KEY0 + (sh_bucket << 13);

    // ---- phase 3: gather composites (key, ~idx) for keys >= Tkey; zero cbuf2
    u.s.cbuf2[tid] = 0ull;
    __syncthreads();
#pragma unroll
    for (int uu = 0; uu < KQT; uu++) {
        uint32_t kk[4] = { kq[uu].x, kq[uu].y, kq[uu].z, kq[uu].w };
#pragma unroll
        for (int j = 0; j < 4; j++) {
            uint32_t key = kk[j];
            if (key >= Tkey) {
                unsigned int p = atomicAdd(&ccount, 1u);
                if (p < SORTN) {
                    unsigned int idx = ((unsigned int)(tid + (uu << 10)) << 2) + (unsigned int)j;
                    u.s.cbuf[p] = ((unsigned long long)key << 32) |
                                  (unsigned long long)(0xFFFFFFFFu - idx);
                }
            }
        }
    }
    __syncthreads();

    // ---- phase 4: rank-by-count scatter (exact desc order; composites are
    // distinct so ranks are a permutation). Broadcast LDS reads, no barriers.
    {
        const unsigned int cnt = (ccount < SORTN) ? ccount : SORTN;
        if ((unsigned int)tid < cnt) {
            unsigned long long ct = u.s.cbuf[tid];
            unsigned int rank = 0;
#pragma unroll 4
            for (unsigned int j = 0; j < cnt; j++)
                rank += (u.s.cbuf[j] > ct) ? 1u : 0u;
            u.s.cbuf2[rank] = ct;
        }
    }
    __syncthreads();

    // ---- phase 5: decode candidates (reference float op order; no fma),
    // plus zero-fill of supm (lower-triangle words must read as 0 in phase 7)
    for (int i2 = tid; i2 < TOPK * 7 + 8; i2 += NT) u.s.supm[i2] = 0ull;
    if (tid < TOPK) {
        const int t = tid;
        unsigned long long c = u.s.cbuf2[t];
        uint32_t key = (uint32_t)(c >> 32);
        uint32_t idx = 0xFFFFFFFFu - (uint32_t)(c & 0xFFFFFFFFull);
        int valid = (key != 0u) && (idx < NN);
        float x1 = 0.f, y1 = 0.f, x2 = 0.f, y2 = 0.f;
        int lab = 0;
        if (valid) {
            const float* p = img + (size_t)idx * CI;
            float l0 = p[0], l1 = p[1], l2 = p[2], l3 = p[3], c0 = p[4], c1 = p[5];
            const float* pr = priors + (size_t)idx * 4;
            float px = pr[0], py = pr[1], pw = pr[2], ph = pr[3];
            float cxv = __fadd_rn(px, __fmul_rn(__fmul_rn(l0, 0.1f), pw));
            float cyv = __fadd_rn(py, __fmul_rn(__fmul_rn(l1, 0.1f), ph));
            float ew = __fmul_rn(pw, expf(__fmul_rn(l2, 0.2f)));
            float eh = __fmul_rn(ph, expf(__fmul_rn(l3, 0.2f)));
            float hw = __fmul_rn(ew, 0.5f);
            float hh = __fmul_rn(eh, 0.5f);
            x1 = __fsub_rn(cxv, hw); y1 = __fsub_rn(cyv, hh);
            x2 = __fadd_rn(cxv, hw); y2 = __fadd_rn(cyv, hh);
            lab = (c1 > c0) ? 1 : 0;
        }
        u.s.cbox[t] = make_float4(x1, y1, x2, y2);
        u.s.csc[t] = __uint_as_float(key);
        u.s.car[t] = __fmul_rn(__fsub_rn(x2, x1), __fsub_rn(y2, y1));
        u.s.clab[t] = lab;
        if (valid) atomicOr(&keepw[t >> 6], 1ull << (t & 63));
    }
    __syncthreads();

    // ---- phase 6: suppression bit-matrix via per-wave ballot.
    // Wave owns rows i = wid, wid+16, ... ; lane tests pair (i, jw*64+lane).
    // bj/aj preloaded once per wave into registers (consecutive-lane reads:
    // conflict-free); cbox[i]/car[i] are same-address broadcasts (free).
    // The 64-bit ballot IS the suppression word. Bit-identical decisions.
    {
        float4 bjv[7]; float ajv[7];
#pragma unroll
        for (int jw = 0; jw < 7; jw++) {
            int j = (jw << 6) + lane;
            int jc = (j < TOPK) ? j : (TOPK - 1);
            bjv[jw] = u.s.cbox[jc];
            ajv[jw] = u.s.car[jc];
        }
        for (int i = wid; i < TOPK; i += 16) {
            float4 bi = u.s.cbox[i];
            float ai = u.s.car[i];
            const int jw0 = i >> 6;           // wave-uniform: scalar branch
#pragma unroll
            for (int jw = 0; jw < 7; jw++) {
                if (jw < jw0) continue;
                int j = (jw << 6) + lane;
                float4 bj = bjv[jw]; float aj = ajv[jw];
                float iw = fmaxf(__fsub_rn(fminf(bi.z, bj.z), fmaxf(bi.x, bj.x)), 0.0f);
                float ih = fmaxf(__fsub_rn(fminf(bi.w, bj.w), fmaxf(bi.y, bj.y)), 0.0f);
                float inter = __fmul_rn(iw, ih);
                float denom = __fadd_rn(__fsub_rn(__fadd_rn(ai, aj), inter), 1e-12f);
                bool bit = (j > i) && (j < TOPK) &&
                           ((double)inter > (double)denom * IOU_C);
                unsigned long long word = __ballot(bit);
                if (lane == 0) u.s.supm[i * 7 + jw] = word;
            }
        }
    }
    __syncthreads();

    // ---- phase 7: sequential resolve, one wave, 16-deep register prefetch
    if (tid < 64) {
        int w = tid & 7;                     // lanes 0-6 own words; rest shadow
        unsigned long long kw = keepw[w];
        unsigned long long rr[16], nn[16];   // compile-time-indexed after unroll
#pragma unroll
        for (int k = 0; k < 16; k++) rr[k] = u.s.supm[k * 7 + w];
        for (int base = 0; base < TOPK; base += 16) {
            int nb = base + 16;
            int gb = (nb < TOPK) ? nb : base;
#pragma unroll
            for (int k = 0; k < 16; k++) nn[k] = u.s.supm[(gb + k) * 7 + w];
#pragma unroll
            for (int k = 0; k < 16; k++) {
                int i = base + k;
                unsigned long long wv = __shfl(kw, i >> 6);
                if ((wv >> (i & 63)) & 1ull) kw &= ~rr[k];
            }
#pragma unroll
            for (int k = 0; k < 16; k++) rr[k] = nn[k];
        }
        if (tid < 7) keepw[tid] = kw;
    }
    __syncthreads();

    // ---- phase 8: rank via suffix-popcount over kept (csc is sorted desc),
    // exact tie correction by local walk (ties are O(0) for float scores).
    if (tid < TOPK) {
        const int t = tid;
        if ((keepw[t >> 6] >> (t & 63)) & 1ull) {
            float st = u.s.csc[t];
            int rank = 0;
#pragma unroll
            for (int w = 0; w < 7; w++) {
                unsigned long long kws = keepw[w];
                int jb = w << 6;
                unsigned long long m;
                if (t >= jb + 63)      m = 0ull;           // no bits > t here
                else if (t < jb)       m = ~0ull;          // whole word > t
                else                   m = ~((1ull << (t - jb + 1)) - 1ull);
                rank += __popcll(kws & m);
            }
            // kept j>t with sj==st were counted but rank below t in ref order
            for (int j = t + 1; j < TOPK && u.s.csc[j] == st; j++)
                if ((keepw[j >> 6] >> (j & 63)) & 1ull) rank--;
            // kept j<t with sj==st rank above t's strict-lower set
            for (int j = t - 1; j >= 0 && u.s.csc[j] == st; j--)
                if ((keepw[j >> 6] >> (j & 63)) & 1ull) rank++;
            if (rank < KEEPK) {
                float4 bx = u.s.cbox[t];
                float* row = oimg + (size_t)rank * 6;
                row[0] = (float)u.s.clab[t];
                row[1] = st;
                row[2] = bx.x; row[3] = bx.y; row[4] = bx.z; row[5] = bx.w;
            }
        }
    }
}

extern "C" void kernel_launch(void* const* d_in, const int* in_sizes, int n_in,
                              void* d_out, int out_size, void* d_ws, size_t ws_size,
                              hipStream_t stream) {
    const float* pred = (const float*)d_in[0];     // (128, 32768, 6)
    const float* priors = (const float*)d_in[1];   // (32768, 4)
    float* out = (float*)d_out;                    // (128, 200, 6)
    uint32_t* keys = (uint32_t*)d_ws;              // 16 MB scratch
    score_kernel<<<(BB * NN / 2) / 256, 256, 0, stream>>>(pred, keys);
    boxsel2_kernel<<<BB, NT, 0, stream>>>(pred, priors, keys, out);
}

// Round 4
// 199.620 us; speedup vs baseline: 1.2788x; 1.0266x over previous
//
#include <hip/hip_runtime.h>
#include <stdint.h>

#define BB 128
#define NN 32768
#define CI 6
#define TOPK 400
#define KEEPK 200
#define SORTN 1024
#define NT 1024
#define KQT 8              // uint4 per thread: 8*4 = 32 keys = NN / NT
#define NBUCK 4096
#define KEY0 0x3F000000u   // float bits of 0.5f
#define STILE 1024         // rows per score block

// Exact-decision IoU constant: RN32(inter/denom) > 0.5f  <=>  inter > denom*(0.5+2^-25),
// and denom(24b) * C(26b) is exact in f64 -> bit-identical keep decisions without v_div.
#define IOU_C 0.50000002980232238769531250

// ---------------- K1: full-GPU score pass, LDS-staged coalescing ----------------
// Block stages 1024 rows (24 KB) via 6 lane-contiguous float4 loads/thread
// (64 lanes x 16B = 1 KiB per instruction, zero wasted requests), then each
// thread extracts conf pairs for rows 4t..4t+3 from LDS and writes one uint4
// of keys (coalesced 16B store). LDS 16-way read conflicts hide under HBM
// service (6 blocks/CU resident).
__global__ __launch_bounds__(256) void score_kernel(
        const float* __restrict__ pred, uint32_t* __restrict__ keys) {
    __shared__ float lf[STILE * 6];                    // 24 KB
    const int t = threadIdx.x;
    const float4* p4 = reinterpret_cast<const float4*>(pred) +
                       (size_t)blockIdx.x * (STILE * 6 / 4);
    float4* l4 = reinterpret_cast<float4*>(lf);
#pragma unroll
    for (int k = 0; k < 6; k++) l4[t + 256 * k] = p4[t + 256 * k];
    __syncthreads();
    uint4 o;
    { float s = fmaxf(lf[24 * t +  4], lf[24 * t +  5]); o.x = (s > 0.5f) ? __float_as_uint(s) : 0u; }
    { float s = fmaxf(lf[24 * t + 10], lf[24 * t + 11]); o.y = (s > 0.5f) ? __float_as_uint(s) : 0u; }
    { float s = fmaxf(lf[24 * t + 16], lf[24 * t + 17]); o.z = (s > 0.5f) ? __float_as_uint(s) : 0u; }
    { float s = fmaxf(lf[24 * t + 22], lf[24 * t + 23]); o.w = (s > 0.5f) ? __float_as_uint(s) : 0u; }
    reinterpret_cast<uint4*>(keys)[blockIdx.x * 256 + t] = o;
}

// ---------------- K2: per-image select + order + decode + NMS ----------------
__global__ __launch_bounds__(NT) void boxsel2_kernel(
        const float* __restrict__ pred, const float* __restrict__ priors,
        const uint32_t* __restrict__ keys, float* __restrict__ out) {
    const int b = blockIdx.x;
    const int tid = threadIdx.x;
    const int lane = tid & 63;
    const int wid = tid >> 6;                 // 0..15
    const float* img = pred + (size_t)b * (NN * CI);
    float* oimg = out + (size_t)b * KEEPK * 6;

    __shared__ union {
        unsigned int hist[4][NBUCK];          // 64 KB, phase 2 only
        struct {                              // phases 3-8 (hist dead)
            unsigned long long cbuf[SORTN];               // gather-order composites
            float4 cbox[TOPK];                            // rank-order
            float car[TOPK], csc[TOPK];
            int clab[TOPK];
            unsigned long long supm[TOPK * 7 + 8];        // stride 7 + pad
        } s;
    } u;
    __shared__ unsigned int wavetot[16];
    __shared__ unsigned int sh_bucket, ccount;
    __shared__ unsigned long long keepw[8];

    // zero output rows (d_out poisoned before every launch)
    for (int i = tid; i < KEEPK * 6; i += NT) oimg[i] = 0.0f;

    // ---- phase 1: coalesced uint4 key load (128 KB per image)
    uint4 kq[KQT];
    const uint4* k4 = reinterpret_cast<const uint4*>(keys + (size_t)b * NN);
#pragma unroll
    for (int uu = 0; uu < KQT; uu++) kq[uu] = k4[tid + (uu << 10)];

    if (tid == 0) { sh_bucket = 0; ccount = 0; }
    for (int i = tid; i < 4 * NBUCK; i += NT) ((unsigned int*)u.hist)[i] = 0u;
    __syncthreads();

    // ---- phase 2a: single-pass histogram, 4 copies (cuts same-bucket chains)
    const int hc = wid & 3;
#pragma unroll
    for (int uu = 0; uu < KQT; uu++) {
        uint32_t k0 = kq[uu].x, k1 = kq[uu].y, k2 = kq[uu].z, k3 = kq[uu].w;
        if (k0) { unsigned int bu = (k0 - KEY0) >> 13; if (bu > NBUCK - 1u) bu = NBUCK - 1u; atomicAdd(&u.hist[hc][bu], 1u); }
        if (k1) { unsigned int bu = (k1 - KEY0) >> 13; if (bu > NBUCK - 1u) bu = NBUCK - 1u; atomicAdd(&u.hist[hc][bu], 1u); }
        if (k2) { unsigned int bu = (k2 - KEY0) >> 13; if (bu > NBUCK - 1u) bu = NBUCK - 1u; atomicAdd(&u.hist[hc][bu], 1u); }
        if (k3) { unsigned int bu = (k3 - KEY0) >> 13; if (bu > NBUCK - 1u) bu = NBUCK - 1u; atomicAdd(&u.hist[hc][bu], 1u); }
    }
    __syncthreads();

    // ---- phase 2b: merge copies + suffix scan; thread owns buckets 4t..4t+3
    unsigned int h0 = u.hist[0][4 * tid + 0] + u.hist[1][4 * tid + 0] + u.hist[2][4 * tid + 0] + u.hist[3][4 * tid + 0];
    unsigned int h1 = u.hist[0][4 * tid + 1] + u.hist[1][4 * tid + 1] + u.hist[2][4 * tid + 1] + u.hist[3][4 * tid + 1];
    unsigned int h2 = u.hist[0][4 * tid + 2] + u.hist[1][4 * tid + 2] + u.hist[2][4 * tid + 2] + u.hist[3][4 * tid + 2];
    unsigned int h3 = u.hist[0][4 * tid + 3] + u.hist[1][4 * tid + 3] + u.hist[2][4 * tid + 3] + u.hist[3][4 * tid + 3];
    unsigned int sum = h0 + h1 + h2 + h3;
    unsigned int suf = sum;                   // wave inclusive suffix sum
#pragma unroll
    for (int off = 1; off < 64; off <<= 1) {
        unsigned int v = __shfl_down(suf, off);
        if (lane + off < 64) suf += v;
    }
    if (lane == 0) wavetot[wid] = suf;
    __syncthreads();
    if (tid < 16) {                           // exclusive suffix over waves
        unsigned int wv = wavetot[tid];
        unsigned int ws = wv;
#pragma unroll
        for (int off = 1; off < 16; off <<= 1) {
            unsigned int v = __shfl_down(ws, off);
            if (tid + off < 16) ws += v;
        }
        wavetot[tid] = ws - wv;
    }
    __syncthreads();
    unsigned int acc = wavetot[wid] + (suf - sum);   // count strictly above my 4
    if (acc < TOPK && acc + h3 >= TOPK) sh_bucket = 4 * tid + 3;
    acc += h3;
    if (acc < TOPK && acc + h2 >= TOPK) sh_bucket = 4 * tid + 2;
    acc += h2;
    if (acc < TOPK && acc + h1 >= TOPK) sh_bucket = 4 * tid + 1;
    acc += h1;
    if (acc < TOPK && acc + h0 >= TOPK) sh_bucket = 4 * tid + 0;
    __syncthreads();
    // bucket(key) >= B  <=>  key >= KEY0 + (B<<13); all stored keys > KEY0.
    const uint32_t Tkey = KEY0 + (sh_bucket << 13);

    // ---- phase 3: gather composites (key, ~idx) for keys >= Tkey
    // (cbuf overlays hist; hist reads completed before the barrier above)
#pragma unroll
    for (int uu = 0; uu < KQT; uu++) {
        uint32_t kk[4] = { kq[uu].x, kq[uu].y, kq[uu].z, kq[uu].w };
#pragma unroll
        for (int j = 0; j < 4; j++) {
            uint32_t key = kk[j];
            if (key >= Tkey) {
                unsigned int p = atomicAdd(&ccount, 1u);
                if (p < SORTN) {
                    unsigned int idx = ((unsigned int)(tid + (uu << 10)) << 2) + (unsigned int)j;
                    u.s.cbuf[p] = ((unsigned long long)key << 32) |
                                  (unsigned long long)(0xFFFFFFFFu - idx);
                }
            }
        }
    }
    __syncthreads();

    // ---- phase 4: fused decode + rank-by-count + permute.
    // Decode loads issue FIRST; the 430-iter rank loop (broadcast LDS reads)
    // covers their latency; results land directly at rank position.
    // Idle threads zero supm; keepw is a computed mask (cnt >= TOPK normally).
    const unsigned int cnt = (ccount < SORTN) ? ccount : SORTN;
    for (int i2 = tid; i2 < TOPK * 7 + 8; i2 += NT) u.s.supm[i2] = 0ull;
    if (tid < 8) {
        int cntc = (cnt < TOPK) ? (int)cnt : TOPK;
        int rem = cntc - (tid << 6);
        keepw[tid] = (rem <= 0) ? 0ull : ((rem >= 64) ? ~0ull : ((1ull << rem) - 1ull));
    }
    if ((unsigned int)tid < cnt) {
        unsigned long long ct = u.s.cbuf[tid];
        uint32_t key = (uint32_t)(ct >> 32);
        uint32_t idx = 0xFFFFFFFFu - (uint32_t)(ct & 0xFFFFFFFFull);
        const float* p = img + (size_t)idx * CI;          // issue scattered loads early
        float l0 = p[0], l1 = p[1], l2 = p[2], l3 = p[3], c0 = p[4], c1 = p[5];
        const float* pr = priors + (size_t)idx * 4;
        float px = pr[0], py = pr[1], pw = pr[2], ph = pr[3];
        unsigned int rank = 0;                            // covers load latency
#pragma unroll 4
        for (unsigned int j = 0; j < cnt; j++)
            rank += (u.s.cbuf[j] > ct) ? 1u : 0u;
        // reference float op order; no fma
        float cxv = __fadd_rn(px, __fmul_rn(__fmul_rn(l0, 0.1f), pw));
        float cyv = __fadd_rn(py, __fmul_rn(__fmul_rn(l1, 0.1f), ph));
        float ew = __fmul_rn(pw, expf(__fmul_rn(l2, 0.2f)));
        float eh = __fmul_rn(ph, expf(__fmul_rn(l3, 0.2f)));
        float hw = __fmul_rn(ew, 0.5f);
        float hh = __fmul_rn(eh, 0.5f);
        float x1 = __fsub_rn(cxv, hw), y1 = __fsub_rn(cyv, hh);
        float x2 = __fadd_rn(cxv, hw), y2 = __fadd_rn(cyv, hh);
        if (rank < TOPK) {
            u.s.cbox[rank] = make_float4(x1, y1, x2, y2);
            u.s.car[rank] = __fmul_rn(__fsub_rn(x2, x1), __fsub_rn(y2, y1));
            u.s.csc[rank] = __uint_as_float(key);
            u.s.clab[rank] = (c1 > c0) ? 1 : 0;
        }
    }
    __syncthreads();

    // ---- phase 6: suppression bit-matrix via per-wave ballot.
    {
        float4 bjv[7]; float ajv[7];
#pragma unroll
        for (int jw = 0; jw < 7; jw++) {
            int j = (jw << 6) + lane;
            int jc = (j < TOPK) ? j : (TOPK - 1);
            bjv[jw] = u.s.cbox[jc];
            ajv[jw] = u.s.car[jc];
        }
        for (int i = wid; i < TOPK; i += 16) {
            float4 bi = u.s.cbox[i];
            float ai = u.s.car[i];
            const int jw0 = i >> 6;           // wave-uniform: scalar branch
#pragma unroll
            for (int jw = 0; jw < 7; jw++) {
                if (jw < jw0) continue;
                int j = (jw << 6) + lane;
                float4 bj = bjv[jw]; float aj = ajv[jw];
                float iw = fmaxf(__fsub_rn(fminf(bi.z, bj.z), fmaxf(bi.x, bj.x)), 0.0f);
                float ih = fmaxf(__fsub_rn(fminf(bi.w, bj.w), fmaxf(bi.y, bj.y)), 0.0f);
                float inter = __fmul_rn(iw, ih);
                float denom = __fadd_rn(__fsub_rn(__fadd_rn(ai, aj), inter), 1e-12f);
                bool bit = (j > i) && (j < TOPK) &&
                           ((double)inter > (double)denom * IOU_C);
                unsigned long long word = __ballot(bit);
                if (lane == 0) u.s.supm[i * 7 + jw] = word;
            }
        }
    }
    __syncthreads();

    // ---- phase 7: sequential resolve; readlane (VALU->SGPR, ~4x lower
    // latency than ds_bpermute __shfl) shortens the 400-step dependent chain.
    if (tid < 64) {
        int w = tid & 7;                     // lanes 0-6 own words; rest shadow
        unsigned long long kw = keepw[w];
        unsigned long long rr[16], nn[16];   // compile-time-indexed after unroll
#pragma unroll
        for (int k = 0; k < 16; k++) rr[k] = u.s.supm[k * 7 + w];
        for (int base = 0; base < TOPK; base += 16) {
            int nb = base + 16;
            int gb = (nb < TOPK) ? nb : base;
#pragma unroll
            for (int k = 0; k < 16; k++) nn[k] = u.s.supm[(gb + k) * 7 + w];
#pragma unroll
            for (int k = 0; k < 16; k++) {
                int i = base + k;
                unsigned int lo = (unsigned int)__builtin_amdgcn_readlane((int)(unsigned int)kw, i >> 6);
                unsigned int hi = (unsigned int)__builtin_amdgcn_readlane((int)(unsigned int)(kw >> 32), i >> 6);
                unsigned int sel = ((i & 63) < 32) ? lo : hi;
                if ((sel >> (i & 31)) & 1u) kw &= ~rr[k];
            }
#pragma unroll
            for (int k = 0; k < 16; k++) rr[k] = nn[k];
        }
        if (tid < 7) keepw[tid] = kw;
    }
    __syncthreads();

    // ---- phase 8: rank via suffix-popcount over kept (csc is sorted desc),
    // exact tie correction by local walk (ties are O(0) for float scores).
    if (tid < TOPK) {
        const int t = tid;
        if ((keepw[t >> 6] >> (t & 63)) & 1ull) {
            float st = u.s.csc[t];
            int rank = 0;
#pragma unroll
            for (int w = 0; w < 7; w++) {
                unsigned long long kws = keepw[w];
                int jb = w << 6;
                unsigned long long m;
                if (t >= jb + 63)      m = 0ull;           // no bits > t here
                else if (t < jb)       m = ~0ull;          // whole word > t
                else                   m = ~((1ull << (t - jb + 1)) - 1ull);
                rank += __popcll(kws & m);
            }
            // kept j>t with sj==st were counted but rank below t in ref order
            for (int j = t + 1; j < TOPK && u.s.csc[j] == st; j++)
                if ((keepw[j >> 6] >> (j & 63)) & 1ull) rank--;
            // kept j<t with sj==st rank above t's strict-lower set
            for (int j = t - 1; j >= 0 && u.s.csc[j] == st; j--)
                if ((keepw[j >> 6] >> (j & 63)) & 1ull) rank++;
            if (rank < KEEPK) {
                float4 bx = u.s.cbox[t];
                float* row = oimg + (size_t)rank * 6;
                row[0] = (float)u.s.clab[t];
                row[1] = st;
                row[2] = bx.x; row[3] = bx.y; row[4] = bx.z; row[5] = bx.w;
            }
        }
    }
}

extern "C" void kernel_launch(void* const* d_in, const int* in_sizes, int n_in,
                              void* d_out, int out_size, void* d_ws, size_t ws_size,
                              hipStream_t stream) {
    const float* pred = (const float*)d_in[0];     // (128, 32768, 6)
    const float* priors = (const float*)d_in[1];   // (32768, 4)
    float* out = (float*)d_out;                    // (128, 200, 6)
    uint32_t* keys = (uint32_t*)d_ws;              // 16 MB scratch
    score_kernel<<<(BB * NN) / STILE, 256, 0, stream>>>(pred, keys);
    boxsel2_kernel<<<BB, NT, 0, stream>>>(pred, priors, keys, out);
}

// Round 5
// 196.907 us; speedup vs baseline: 1.2964x; 1.0138x over previous
//
#include <hip/hip_runtime.h>
#include <stdint.h>

#define BB 128
#define NN 32768
#define CI 6
#define TOPK 400
#define PADK 448           // TOPK padded to full 64-lane words (zero boxes)
#define KEEPK 200
#define SORTN 1024
#define NT 1024
#define KQT 8              // uint4 per thread: 8*4 = 32 keys = NN / NT
#define NBUCK 4096
#define KEY0 0x3F000000u   // float bits of 0.5f
#define STILE 1024         // rows per score block

// Exact-decision IoU constant: RN32(inter/denom) > 0.5f  <=>  inter > denom*(0.5+2^-25),
// and denom(24b) * C(26b) is exact in f64 -> bit-identical keep decisions without v_div.
#define IOU_C 0.50000002980232238769531250

// ---------------- K1: full-GPU score pass, LDS-staged coalescing ----------------
__global__ __launch_bounds__(256) void score_kernel(
        const float* __restrict__ pred, uint32_t* __restrict__ keys) {
    __shared__ float lf[STILE * 6];                    // 24 KB
    const int t = threadIdx.x;
    const float4* p4 = reinterpret_cast<const float4*>(pred) +
                       (size_t)blockIdx.x * (STILE * 6 / 4);
    float4* l4 = reinterpret_cast<float4*>(lf);
#pragma unroll
    for (int k = 0; k < 6; k++) l4[t + 256 * k] = p4[t + 256 * k];
    __syncthreads();
    uint4 o;
    { float s = fmaxf(lf[24 * t +  4], lf[24 * t +  5]); o.x = (s > 0.5f) ? __float_as_uint(s) : 0u; }
    { float s = fmaxf(lf[24 * t + 10], lf[24 * t + 11]); o.y = (s > 0.5f) ? __float_as_uint(s) : 0u; }
    { float s = fmaxf(lf[24 * t + 16], lf[24 * t + 17]); o.z = (s > 0.5f) ? __float_as_uint(s) : 0u; }
    { float s = fmaxf(lf[24 * t + 22], lf[24 * t + 23]); o.w = (s > 0.5f) ? __float_as_uint(s) : 0u; }
    reinterpret_cast<uint4*>(keys)[blockIdx.x * 256 + t] = o;
}

// ---------------- K2: per-image select + order + decode + NMS ----------------
__global__ __launch_bounds__(NT) void boxsel2_kernel(
        const float* __restrict__ pred, const float* __restrict__ priors,
        const uint32_t* __restrict__ keys, float* __restrict__ out) {
    const int b = blockIdx.x;
    const int tid = threadIdx.x;
    const int lane = tid & 63;
    const int wid = tid >> 6;                 // 0..15
    const float* img = pred + (size_t)b * (NN * CI);
    float* oimg = out + (size_t)b * KEEPK * 6;

    __shared__ union {
        unsigned int hist[4][NBUCK];          // 64 KB, phase 2 only
        struct {                              // phases 3-8 (hist dead)
            unsigned long long cbuf[SORTN];               // gather-order composites
            float4 cbox[PADK];                            // rank-order, zero pad
            float car[PADK], csc[TOPK];
            int clab[TOPK];
            unsigned long long supm[TOPK * 7 + 8];        // stride 7 + pad
        } s;
    } u;
    __shared__ unsigned int wavetot[16];
    __shared__ unsigned int sh_bucket, ccount;
    __shared__ unsigned long long keepw[8];

    // zero output rows (d_out poisoned before every launch)
    for (int i = tid; i < KEEPK * 6; i += NT) oimg[i] = 0.0f;

    // ---- phase 1: coalesced uint4 key load (128 KB per image)
    uint4 kq[KQT];
    const uint4* k4 = reinterpret_cast<const uint4*>(keys + (size_t)b * NN);
#pragma unroll
    for (int uu = 0; uu < KQT; uu++) kq[uu] = k4[tid + (uu << 10)];

    if (tid == 0) { sh_bucket = 0; ccount = 0; }
    for (int i = tid; i < 4 * NBUCK; i += NT) ((unsigned int*)u.hist)[i] = 0u;
    __syncthreads();

    // ---- phase 2a: single-pass histogram, 4 copies (cuts same-bucket chains)
    const int hc = wid & 3;
#pragma unroll
    for (int uu = 0; uu < KQT; uu++) {
        uint32_t k0 = kq[uu].x, k1 = kq[uu].y, k2 = kq[uu].z, k3 = kq[uu].w;
        if (k0) { unsigned int bu = (k0 - KEY0) >> 13; if (bu > NBUCK - 1u) bu = NBUCK - 1u; atomicAdd(&u.hist[hc][bu], 1u); }
        if (k1) { unsigned int bu = (k1 - KEY0) >> 13; if (bu > NBUCK - 1u) bu = NBUCK - 1u; atomicAdd(&u.hist[hc][bu], 1u); }
        if (k2) { unsigned int bu = (k2 - KEY0) >> 13; if (bu > NBUCK - 1u) bu = NBUCK - 1u; atomicAdd(&u.hist[hc][bu], 1u); }
        if (k3) { unsigned int bu = (k3 - KEY0) >> 13; if (bu > NBUCK - 1u) bu = NBUCK - 1u; atomicAdd(&u.hist[hc][bu], 1u); }
    }
    __syncthreads();

    // ---- phase 2b: merge copies + suffix scan; thread owns buckets 4t..4t+3
    unsigned int h0 = u.hist[0][4 * tid + 0] + u.hist[1][4 * tid + 0] + u.hist[2][4 * tid + 0] + u.hist[3][4 * tid + 0];
    unsigned int h1 = u.hist[0][4 * tid + 1] + u.hist[1][4 * tid + 1] + u.hist[2][4 * tid + 1] + u.hist[3][4 * tid + 1];
    unsigned int h2 = u.hist[0][4 * tid + 2] + u.hist[1][4 * tid + 2] + u.hist[2][4 * tid + 2] + u.hist[3][4 * tid + 2];
    unsigned int h3 = u.hist[0][4 * tid + 3] + u.hist[1][4 * tid + 3] + u.hist[2][4 * tid + 3] + u.hist[3][4 * tid + 3];
    unsigned int sum = h0 + h1 + h2 + h3;
    unsigned int suf = sum;                   // wave inclusive suffix sum
#pragma unroll
    for (int off = 1; off < 64; off <<= 1) {
        unsigned int v = __shfl_down(suf, off);
        if (lane + off < 64) suf += v;
    }
    if (lane == 0) wavetot[wid] = suf;
    __syncthreads();
    if (tid < 16) {                           // exclusive suffix over waves
        unsigned int wv = wavetot[tid];
        unsigned int ws = wv;
#pragma unroll
        for (int off = 1; off < 16; off <<= 1) {
            unsigned int v = __shfl_down(ws, off);
            if (tid + off < 16) ws += v;
        }
        wavetot[tid] = ws - wv;
    }
    __syncthreads();
    unsigned int acc = wavetot[wid] + (suf - sum);   // count strictly above my 4
    if (acc < TOPK && acc + h3 >= TOPK) sh_bucket = 4 * tid + 3;
    acc += h3;
    if (acc < TOPK && acc + h2 >= TOPK) sh_bucket = 4 * tid + 2;
    acc += h2;
    if (acc < TOPK && acc + h1 >= TOPK) sh_bucket = 4 * tid + 1;
    acc += h1;
    if (acc < TOPK && acc + h0 >= TOPK) sh_bucket = 4 * tid + 0;
    __syncthreads();
    // bucket(key) >= B  <=>  key >= KEY0 + (B<<13); all stored keys > KEY0.
    const uint32_t Tkey = KEY0 + (sh_bucket << 13);

    // ---- phase 3: gather composites (key, ~idx) for keys >= Tkey
#pragma unroll
    for (int uu = 0; uu < KQT; uu++) {
        uint32_t kk[4] = { kq[uu].x, kq[uu].y, kq[uu].z, kq[uu].w };
#pragma unroll
        for (int j = 0; j < 4; j++) {
            uint32_t key = kk[j];
            if (key >= Tkey) {
                unsigned int p = atomicAdd(&ccount, 1u);
                if (p < SORTN) {
                    unsigned int idx = ((unsigned int)(tid + (uu << 10)) << 2) + (unsigned int)j;
                    u.s.cbuf[p] = ((unsigned long long)key << 32) |
                                  (unsigned long long)(0xFFFFFFFFu - idx);
                }
            }
        }
    }
    __syncthreads();

    // ---- phase 4: fused decode + rank-by-count (x2 vectorized) + permute.
    // Decode loads issue FIRST; rank loop (broadcast LDS b128 reads) covers
    // their latency; results land directly at rank position. Idle threads
    // zero supm and the candidate pad; keepw is a computed mask.
    const unsigned int cnt = (ccount < SORTN) ? ccount : SORTN;
    for (int i2 = tid; i2 < TOPK * 7 + 8; i2 += NT) u.s.supm[i2] = 0ull;
    if (tid >= TOPK && tid < PADK) {          // zero pad: never suppresses
        u.s.cbox[tid] = make_float4(0.f, 0.f, 0.f, 0.f);
        u.s.car[tid] = 0.f;
    }
    if (tid < 8) {
        int cntc = (cnt < TOPK) ? (int)cnt : TOPK;
        int rem = cntc - (tid << 6);
        keepw[tid] = (rem <= 0) ? 0ull : ((rem >= 64) ? ~0ull : ((1ull << rem) - 1ull));
    }
    if ((unsigned int)tid < cnt) {
        unsigned long long ct = u.s.cbuf[tid];
        uint32_t key = (uint32_t)(ct >> 32);
        uint32_t idx = 0xFFFFFFFFu - (uint32_t)(ct & 0xFFFFFFFFull);
        const float* p = img + (size_t)idx * CI;          // issue scattered loads early
        float l0 = p[0], l1 = p[1], l2 = p[2], l3 = p[3], c0 = p[4], c1 = p[5];
        const float* pr = priors + (size_t)idx * 4;
        float px = pr[0], py = pr[1], pw = pr[2], ph = pr[3];
        unsigned int rank = 0;                            // covers load latency
        const ulonglong2* c2 = reinterpret_cast<const ulonglong2*>(u.s.cbuf);
        unsigned int half = cnt >> 1;
#pragma unroll 4
        for (unsigned int m = 0; m < half; m++) {
            ulonglong2 v = c2[m];
            rank += (v.x > ct) ? 1u : 0u;
            rank += (v.y > ct) ? 1u : 0u;
        }
        if (cnt & 1) rank += (u.s.cbuf[cnt - 1] > ct) ? 1u : 0u;
        // reference float op order; no fma
        float cxv = __fadd_rn(px, __fmul_rn(__fmul_rn(l0, 0.1f), pw));
        float cyv = __fadd_rn(py, __fmul_rn(__fmul_rn(l1, 0.1f), ph));
        float ew = __fmul_rn(pw, expf(__fmul_rn(l2, 0.2f)));
        float eh = __fmul_rn(ph, expf(__fmul_rn(l3, 0.2f)));
        float hw = __fmul_rn(ew, 0.5f);
        float hh = __fmul_rn(eh, 0.5f);
        float x1 = __fsub_rn(cxv, hw), y1 = __fsub_rn(cyv, hh);
        float x2 = __fadd_rn(cxv, hw), y2 = __fadd_rn(cyv, hh);
        if (rank < TOPK) {
            u.s.cbox[rank] = make_float4(x1, y1, x2, y2);
            u.s.car[rank] = __fmul_rn(__fsub_rn(x2, x1), __fsub_rn(y2, y1));
            u.s.csc[rank] = __uint_as_float(key);
            u.s.clab[rank] = (c1 > c0) ? 1 : 0;
        }
    }
    __syncthreads();

    // ---- phase 6: suppression bit-matrix via per-wave ballot.
    // Columns padded to 448 zero-boxes -> no (j<TOPK) test; (j>i) handled by
    // masking the diagonal word once per row, outside the pair loop.
    {
        float4 bjv[7]; float ajv[7];
#pragma unroll
        for (int jw = 0; jw < 7; jw++) {
            int j = (jw << 6) + lane;
            bjv[jw] = u.s.cbox[j];
            ajv[jw] = u.s.car[j];
        }
        float4 bi = u.s.cbox[wid];
        float ai = u.s.car[wid];
        for (int i = wid; i < TOPK; i += 16) {
            float4 bi_n = u.s.cbox[i + 16];   // prefetch next row (pad-safe)
            float ai_n = u.s.car[i + 16];
            const int jw0 = i >> 6;           // wave-uniform
            // diagonal-word mask: keep bits j > i only (double shift: no UB)
            unsigned long long dmask = (~0ull << (i & 63)) << 1;
#pragma unroll
            for (int jw = 0; jw < 7; jw++) {
                if (jw < jw0) continue;
                float4 bj = bjv[jw]; float aj = ajv[jw];
                float iw = fmaxf(__fsub_rn(fminf(bi.z, bj.z), fmaxf(bi.x, bj.x)), 0.0f);
                float ih = fmaxf(__fsub_rn(fminf(bi.w, bj.w), fmaxf(bi.y, bj.y)), 0.0f);
                float inter = __fmul_rn(iw, ih);
                float denom = __fadd_rn(__fsub_rn(__fadd_rn(ai, aj), inter), 1e-12f);
                bool bit = (double)inter > (double)denom * IOU_C;
                unsigned long long word = __ballot(bit);
                if (lane == 0) {
                    if (jw == jw0) word &= dmask;
                    u.s.supm[i * 7 + jw] = word;
                }
            }
            bi = bi_n; ai = ai_n;
        }
    }
    __syncthreads();

    // ---- phase 7: sequential resolve; readlane (VALU->SGPR) chain
    if (tid < 64) {
        int w = tid & 7;                     // lanes 0-6 own words; rest shadow
        unsigned long long kw = keepw[w];
        unsigned long long rr[16], nn[16];   // compile-time-indexed after unroll
#pragma unroll
        for (int k = 0; k < 16; k++) rr[k] = u.s.supm[k * 7 + w];
        for (int base = 0; base < TOPK; base += 16) {
            int nb = base + 16;
            int gb = (nb < TOPK) ? nb : base;
#pragma unroll
            for (int k = 0; k < 16; k++) nn[k] = u.s.supm[(gb + k) * 7 + w];
#pragma unroll
            for (int k = 0; k < 16; k++) {
                int i = base + k;
                unsigned int lo = (unsigned int)__builtin_amdgcn_readlane((int)(unsigned int)kw, i >> 6);
                unsigned int hi = (unsigned int)__builtin_amdgcn_readlane((int)(unsigned int)(kw >> 32), i >> 6);
                unsigned int sel = ((i & 63) < 32) ? lo : hi;
                if ((sel >> (i & 31)) & 1u) kw &= ~rr[k];
            }
#pragma unroll
            for (int k = 0; k < 16; k++) rr[k] = nn[k];
        }
        if (tid < 7) keepw[tid] = kw;
    }
    __syncthreads();

    // ---- phase 8: rank via suffix-popcount over kept (csc is sorted desc),
    // exact tie correction by local walk (ties are O(0) for float scores).
    if (tid < TOPK) {
        const int t = tid;
        if ((keepw[t >> 6] >> (t & 63)) & 1ull) {
            float st = u.s.csc[t];
            int rank = 0;
#pragma unroll
            for (int w = 0; w < 7; w++) {
                unsigned long long kws = keepw[w];
                int jb = w << 6;
                unsigned long long m;
                if (t >= jb + 63)      m = 0ull;           // no bits > t here
                else if (t < jb)       m = ~0ull;          // whole word > t
                else                   m = ~((1ull << (t - jb + 1)) - 1ull);
                rank += __popcll(kws & m);
            }
            for (int j = t + 1; j < TOPK && u.s.csc[j] == st; j++)
                if ((keepw[j >> 6] >> (j & 63)) & 1ull) rank--;
            for (int j = t - 1; j >= 0 && u.s.csc[j] == st; j--)
                if ((keepw[j >> 6] >> (j & 63)) & 1ull) rank++;
            if (rank < KEEPK) {
                float4 bx = u.s.cbox[t];
                float* row = oimg + (size_t)rank * 6;
                row[0] = (float)u.s.clab[t];
                row[1] = st;
                row[2] = bx.x; row[3] = bx.y; row[4] = bx.z; row[5] = bx.w;
            }
        }
    }
}

extern "C" void kernel_launch(void* const* d_in, const int* in_sizes, int n_in,
                              void* d_out, int out_size, void* d_ws, size_t ws_size,
                              hipStream_t stream) {
    const float* pred = (const float*)d_in[0];     // (128, 32768, 6)
    const float* priors = (const float*)d_in[1];   // (32768, 4)
    float* out = (float*)d_out;                    // (128, 200, 6)
    uint32_t* keys = (uint32_t*)d_ws;              // 16 MB scratch
    score_kernel<<<(BB * NN) / STILE, 256, 0, stream>>>(pred, keys);
    boxsel2_kernel<<<BB, NT, 0, stream>>>(pred, priors, keys, out);
}